// Round 1
// 26.072 us; speedup vs baseline: 1.0904x; 1.0904x over previous
//
#include <hip/hip_runtime.h>
#include <hip/hip_bf16.h>
#include <hip/hip_fp16.h>

#define NNODES 1024
#define FDIM   64
#define KOUT   32
#define NI     32          // i-rows per block (LDS tile)

typedef _Float16 f16x8 __attribute__((ext_vector_type(8)));
typedef _Float16 f16x4 __attribute__((ext_vector_type(4)));
typedef float    f32x4 __attribute__((ext_vector_type(4)));

// ---------------- fused kernel: per-block L/R projection + pairwise MLP -----
// Phase A: stage the 96 emb rows this block needs (32 i-rows, 64 j-rows) into
//   LDS as fp16 (stride 72 halves = 144 B keeps b128 frag reads at the
//   minimum 8-phase pattern), then compute
//     left[i,:]  = emb[i,:] @ W1[:F]  + b1     (i0..i0+31)
//     right[j,:] = emb[j,:] @ W1[F:]           (j0..j0+63)
//   with 12 MFMAs/wave (wave w owns output columns 16w..16w+15; W1 column
//   fragments are loaded straight from global — 32 KB, L2-hot).
// Phase B: identical to the previous pair_mlp_kernel main loop.
__global__ __launch_bounds__(256) void fused_pair_mlp(
    const float* __restrict__ emb, const float* __restrict__ W1,
    const float* __restrict__ b1,
    const float* __restrict__ W2, const float* __restrict__ b2,
    const float* __restrict__ W3, const float* __restrict__ b3,
    float* __restrict__ out)
{
    const int tid  = threadIdx.x;
    const int wv   = tid >> 6;      // wave id 0..3
    const int ln   = tid & 63;
    const int ln16 = ln & 15;
    const int grp  = ln >> 4;       // k-group of 8

    const int b  = blockIdx.z;
    const int j0 = blockIdx.x * 64;      // 4 waves x 16 j
    const int i0 = blockIdx.y * NI;

    __shared__ _Float16 semb[96][72];       // 13.5 KiB staged emb rows (fp16)
    __shared__ _Float16 lleft[NI][FDIM];    // 4 KiB
    __shared__ _Float16 rtile[64][FDIM];    // 8 KiB

    // ---- phase A1: stage emb rows (rows 0..31 = i-tile, 32..95 = j-tile) ----
    {
        const float* ebase = emb + (size_t)b * NNODES * FDIM;
#pragma unroll
        for (int q = 0; q < 6; ++q) {
            const int idx  = q * 256 + tid;       // [0,1536) float4s
            const int row  = idx >> 4;            // [0,96)
            const int c4   = idx & 15;
            const int grow = (row < 32) ? (i0 + row) : (j0 + row - 32);
            const float4 v = *(const float4*)(ebase + (size_t)grow * FDIM + c4 * 4);
            f16x4 hv = { (_Float16)v.x, (_Float16)v.y, (_Float16)v.z, (_Float16)v.w };
            *(f16x4*)(&semb[row][c4 * 4]) = hv;   // 8B write, 16/8B aligned
        }
    }

    // ---- W1 B-frags for this wave's output columns (global, L2-hot) ----
    const int ow = wv * 16 + ln16;        // output feature column of this lane
    f16x8 bW1L[2], bW1R[2];               // [k-half]
#pragma unroll
    for (int s = 0; s < 2; ++s)
#pragma unroll
        for (int e = 0; e < 8; ++e) {
            bW1L[s][e] = (_Float16)W1[(s * 32 + grp * 8 + e) * FDIM + ow];
            bW1R[s][e] = (_Float16)W1[(64 + s * 32 + grp * 8 + e) * FDIM + ow];
        }
    const float b1v = b1[ow];

    // ---- A-frags: W2^T, aW[k2tile t][khalf s] (unchanged) ----
    f16x8 aW[2][2];
#pragma unroll
    for (int t = 0; t < 2; ++t)
#pragma unroll
        for (int s = 0; s < 2; ++s)
#pragma unroll
            for (int e = 0; e < 8; ++e)
                aW[t][s][e] = (_Float16)W2[(s * 32 + grp * 8 + e) * KOUT
                                           + t * 16 + ln16];

    // ---- per-lane C-init (b2 folded) and W3 epilogue weights (unchanged) ----
    f32x4 c0i, c1i;
    float wa[8], wb[8];
#pragma unroll
    for (int r = 0; r < 4; ++r) {
        c0i[r] = b2[grp * 4 + r];
        c1i[r] = b2[16 + grp * 4 + r];
        const float w3lo = W3[grp * 4 + r];
        const float w3hi = W3[16 + grp * 4 + r];
        wa[r]     = 0.505f * w3lo;  wb[r]     = 0.495f * w3lo;
        wa[r + 4] = 0.505f * w3hi;  wb[r + 4] = 0.495f * w3hi;
    }
    const float bias3 = b3[0];

    __syncthreads();

    // ---- phase A2: left tiles (2 m-tiles) ----
#pragma unroll
    for (int mt = 0; mt < 2; ++mt) {
        const _Float16* ap = &semb[mt * 16 + ln16][grp * 8];
        const f16x8 a0 = *(const f16x8*)ap;          // f = grp*8+e
        const f16x8 a1 = *(const f16x8*)(ap + 32);   // f = 32+grp*8+e
        f32x4 acc = {0.f, 0.f, 0.f, 0.f};
        acc = __builtin_amdgcn_mfma_f32_16x16x32_f16(a0, bW1L[0], acc, 0, 0, 0);
        acc = __builtin_amdgcn_mfma_f32_16x16x32_f16(a1, bW1L[1], acc, 0, 0, 0);
#pragma unroll
        for (int r = 0; r < 4; ++r)
            lleft[mt * 16 + grp * 4 + r][ow] = (_Float16)(acc[r] + b1v);
    }
    // ---- phase A2: right tiles (4 m-tiles) ----
#pragma unroll
    for (int mt = 0; mt < 4; ++mt) {
        const _Float16* ap = &semb[32 + mt * 16 + ln16][grp * 8];
        const f16x8 a0 = *(const f16x8*)ap;
        const f16x8 a1 = *(const f16x8*)(ap + 32);
        f32x4 acc = {0.f, 0.f, 0.f, 0.f};
        acc = __builtin_amdgcn_mfma_f32_16x16x32_f16(a0, bW1R[0], acc, 0, 0, 0);
        acc = __builtin_amdgcn_mfma_f32_16x16x32_f16(a1, bW1R[1], acc, 0, 0, 0);
#pragma unroll
        for (int r = 0; r < 4; ++r)
            rtile[mt * 16 + grp * 4 + r][ow] = (_Float16)acc[r];
    }

    __syncthreads();

    // ---- this lane's right-row slice (j = j0 + wv*16 + ln16), now from LDS --
    const int jj = j0 + wv * 16 + ln16;
    const _Float16* rp = &rtile[wv * 16 + ln16][0];
    const f16x8 r0 = *(const f16x8*)(rp + grp * 8);
    const f16x8 r1 = *(const f16x8*)(rp + 32 + grp * 8);

    const _Float16 slope = (_Float16)0.01f;

    // ---- phase B: pairwise MLP main loop (unchanged) ----
#pragma unroll 2
    for (int ii = 0; ii < NI; ++ii) {
        const _Float16* lrow = &lleft[ii][0];
        const f16x8 l0 = *(const f16x8*)(lrow + grp * 8);
        const f16x8 l1 = *(const f16x8*)(lrow + 32 + grp * 8);

        // h = leaky(l + r) in packed fp16
        f16x8 h0 = l0 + r0;
        f16x8 h1 = l1 + r1;
        h0 = __builtin_elementwise_max(h0, h0 * slope);
        h1 = __builtin_elementwise_max(h1, h1 * slope);

        f32x4 acc0 = c0i;
        f32x4 acc1 = c1i;
        acc0 = __builtin_amdgcn_mfma_f32_16x16x32_f16(aW[0][0], h0, acc0, 0, 0, 0);
        acc0 = __builtin_amdgcn_mfma_f32_16x16x32_f16(aW[0][1], h1, acc0, 0, 0, 0);
        acc1 = __builtin_amdgcn_mfma_f32_16x16x32_f16(aW[1][0], h0, acc1, 0, 0, 0);
        acc1 = __builtin_amdgcn_mfma_f32_16x16x32_f16(aW[1][1], h1, acc1, 0, 0, 0);

        // epilogue: p(j) = sum_k2 leaky(h2[k2]) * W3[k2]
        // leaky(x)*w = (0.505w)x + (0.495w)|x|  -> fma with free abs modifier
        float p = 0.f;
#pragma unroll
        for (int r = 0; r < 4; ++r) {
            p = fmaf(wa[r],     acc0[r],        p);
            p = fmaf(wb[r],     fabsf(acc0[r]), p);
            p = fmaf(wa[r + 4], acc1[r],        p);
            p = fmaf(wb[r + 4], fabsf(acc1[r]), p);
        }
        // reduce over the 4 k-groups (lanes ln16 aligned, grp differs)
        p += __shfl_xor(p, 16, 64);
        p += __shfl_xor(p, 32, 64);
        if (grp == 0)
            out[((size_t)b * NNODES + (i0 + ii)) * NNODES + jj] = p + bias3;
    }
}

extern "C" void kernel_launch(void* const* d_in, const int* in_sizes, int n_in,
                              void* d_out, int out_size, void* d_ws, size_t ws_size,
                              hipStream_t stream) {
    const float* emb = (const float*)d_in[0];
    const float* W1  = (const float*)d_in[1];
    const float* b1  = (const float*)d_in[2];
    const float* W2  = (const float*)d_in[3];
    const float* b2  = (const float*)d_in[4];
    const float* W3  = (const float*)d_in[5];
    const float* b3  = (const float*)d_in[6];
    float* out = (float*)d_out;
    (void)d_ws; (void)ws_size;

    fused_pair_mlp<<<dim3(NNODES / 64, NNODES / NI, 2), dim3(256), 0, stream>>>(
        emb, W1, b1, W2, b2, W3, b3, out);
}